// Round 11
// baseline (83.198 us; speedup 1.0000x reference)
//
#include <hip/hip_runtime.h>
#include <hip/hip_cooperative_groups.h>

namespace cg = cooperative_groups;

#define INFV 3.0e38f

// ws slot layout (floats) — every slot written unconditionally each call
#define W_D1S 0     // 256: d1 masked sqrt-sum per (b, ic16)
#define W_D1C 256   // 256: mask count per (b, ic16)
#define W_D2S 512   // 256: d2 sqrt-sum per (b, oc16)
#define W_CDP 768   // 32: cd partial per (b, half)
#define W_DIV 800   // 16
#define W_DEL 816   // 16
#define W_POSE 832
#define W_NOCS 833
#define W_DIST 834

__device__ __forceinline__ float wave_reduce_sum(float v) {
#pragma unroll
    for (int m = 1; m < 64; m <<= 1) v += __shfl_xor(v, m);
    return v;
}

// block-wide sum (256 threads)
__device__ __forceinline__ float block_sum_t0(float v, float* sbuf) {
    v = wave_reduce_sum(v);
    int lane = threadIdx.x & 63, wid = threadIdx.x >> 6;
    __syncthreads();
    if (lane == 0) sbuf[wid] = v;
    __syncthreads();
    return sbuf[0] + sbuf[1] + sbuf[2] + sbuf[3];
}

// dual block-wide sum in one barrier round
__device__ __forceinline__ void block_sum2_t0(float v1, float v2, float* sbuf,
                                              float* r1, float* r2) {
    v1 = wave_reduce_sum(v1);
    v2 = wave_reduce_sum(v2);
    int lane = threadIdx.x & 63, wid = threadIdx.x >> 6;
    __syncthreads();
    if (lane == 0) { sbuf[wid] = v1; sbuf[4 + wid] = v2; }
    __syncthreads();
    *r1 = sbuf[0] + sbuf[1] + sbuf[2] + sbuf[3];
    *r2 = sbuf[4] + sbuf[5] + sbuf[6] + sbuf[7];
}

// pc_mask may arrive as u8 (1B) or i32 (4B). Probe bytes at 4i+1 (wave-wide).
__device__ __forceinline__ bool mask_mode_u8(const void* mp) {
    const unsigned char* p = (const unsigned char*)mp;
    unsigned char v = p[(threadIdx.x & 63) * 4 + 1];
    return __ballot(v != 0) != 0ull;
}
__device__ __forceinline__ bool mask_at(const void* mp, int idx, bool u8) {
    if (u8) return ((const unsigned char*)mp)[idx] != 0;
    return ((const int*)mp)[idx] != 0;
}

// unpack 3 float4 (12 floats) into 4 xyz points
#define UNPACK12(f0, f1, f2, X, Y, Z) { \
    X[0]=f0.x; Y[0]=f0.y; Z[0]=f0.z; \
    X[1]=f0.w; Y[1]=f1.x; Z[1]=f1.y; \
    X[2]=f1.z; Y[2]=f1.w; Z[2]=f2.x; \
    X[3]=f2.y; Y[3]=f2.z; Z[3]=f2.w; }

// 4-query scan over this thread's j-class (64 staged points, stride 16)
__device__ __forceinline__ void scan4(const float4* lds4, int jc,
                                      const float* ax, const float* ay,
                                      const float* az, float* mm) {
    for (int r = 0; r < 64; r += 4) {
        float4 q0 = lds4[((r + 0) << 4) + jc];
        float4 q1 = lds4[((r + 1) << 4) + jc];
        float4 q2 = lds4[((r + 2) << 4) + jc];
        float4 q3 = lds4[((r + 3) << 4) + jc];
#pragma unroll
        for (int u = 0; u < 4; ++u)
            mm[u] = fminf(mm[u], fmaf(ax[u], q0.x, fmaf(ay[u], q0.y, fmaf(az[u], q0.z, q0.w))));
#pragma unroll
        for (int u = 0; u < 4; ++u)
            mm[u] = fminf(mm[u], fmaf(ax[u], q1.x, fmaf(ay[u], q1.y, fmaf(az[u], q1.z, q1.w))));
#pragma unroll
        for (int u = 0; u < 4; ++u)
            mm[u] = fminf(mm[u], fmaf(ax[u], q2.x, fmaf(ay[u], q2.y, fmaf(az[u], q2.z, q2.w))));
#pragma unroll
        for (int u = 0; u < 4; ++u)
            mm[u] = fminf(mm[u], fmaf(ax[u], q3.x, fmaf(ay[u], q3.y, fmaf(az[u], q3.z, q3.w))));
    }
}

// load 4 consecutive points as 3 float4, derive scan coefficients
__device__ __forceinline__ void load_queries4(const float* base,
                                              float* ax, float* ay, float* az,
                                              float* pw, float* mm) {
    const float4* q4 = (const float4*)base;
    float4 g0 = q4[0], g1 = q4[1], g2 = q4[2];
    float X[4], Y[4], Z[4];
    UNPACK12(g0, g1, g2, X, Y, Z);
#pragma unroll
    for (int u = 0; u < 4; ++u) {
        ax[u] = -2.0f * X[u]; ay[u] = -2.0f * Y[u]; az[u] = -2.0f * Z[u];
        pw[u] = fmaf(X[u], X[u], fmaf(Y[u], Y[u], Z[u] * Z[u]));
        mm[u] = INFV;
    }
}

__global__ __launch_bounds__(256) void loss_main(
    const float* __restrict__ pts,          // (16,1024,3)
    const float* __restrict__ recon_delta,  // (16,1024,3)
    const float* __restrict__ kpt,          // (16,96,3)
    const float* __restrict__ recon,        // (16,1024,3)
    const float* __restrict__ t_label,      // (16,3)
    const float* __restrict__ r_label,      // (16,3,3)
    const float* __restrict__ s_label,      // (16,3)
    const float* __restrict__ pred_r,       // (16,3,3)
    const float* __restrict__ pred_t,       // (16,3)
    const float* __restrict__ pred_s,       // (16,3)
    const float* __restrict__ kpt_nocs,     // (16,96,3)
    const void*  __restrict__ pc_mask,      // (16,1024) bool
    const float* __restrict__ d_pn,         // (16,512)
    const float* __restrict__ d_ul,         // (16,512)
    float* __restrict__ ws,
    float* __restrict__ out)
{
    __shared__ float4 lds4[1024];
    __shared__ float pminS[1088];   // 64 rows x stride 17 (pad -> conflict-free)
    __shared__ float sbuf[8];
    const int t = threadIdx.x;
    const int blk = blockIdx.x;

    if (blk < 256) {
        // ---- d1: block=(b, ic of 16). Stage ALL 1024 recon pts of b.
        int b = blk >> 4, ic = blk & 15;
        bool u8 = mask_mode_u8(pc_mask);
        {
            const float4* p4 = (const float4*)(recon + (b << 10) * 3);
            float4 f0 = p4[3 * t], f1 = p4[3 * t + 1], f2 = p4[3 * t + 2];
            float X[4], Y[4], Z[4];
            UNPACK12(f0, f1, f2, X, Y, Z);
#pragma unroll
            for (int u = 0; u < 4; ++u)
                lds4[4 * t + u] = make_float4(X[u], Y[u], Z[u],
                    fmaf(X[u], X[u], fmaf(Y[u], Y[u], Z[u] * Z[u])));
        }
        int tg = t >> 4, jc = t & 15;
        int i0 = (ic << 6) + (tg << 2);       // 4 queries per thread
        float ax[4], ay[4], az[4], pw[4], mm[4];
        load_queries4(pts + ((b << 10) + i0) * 3, ax, ay, az, pw, mm);
        __syncthreads();
        scan4(lds4, jc, ax, ay, az, mm);
#pragma unroll
        for (int u = 0; u < 4; ++u)
            pminS[(tg * 4 + u) * 17 + jc] = pw[u] + mm[u];
        __syncthreads();
        float contrib_s = 0.0f, contrib_c = 0.0f;
        if (t < 64) {
            float v = INFV;
#pragma unroll
            for (int c = 0; c < 16; ++c) v = fminf(v, pminS[t * 17 + c]);
            float d = sqrtf(fmaxf(0.0f, v));
            float mv = mask_at(pc_mask, (b << 10) + (ic << 6) + t, u8) ? 1.0f : 0.0f;
            contrib_s = d * mv;
            contrib_c = mv;
        }
        float s, c;
        block_sum2_t0(contrib_s, contrib_c, sbuf, &s, &c);
        if (t == 0) { ws[W_D1S + blk] = s; ws[W_D1C + blk] = c; }

    } else if (blk < 512) {
        // ---- d2: block=(b, oc of 16). Stage ALL 1024 pts masked->(0,0,0,3e36).
        int bb = blk - 256;
        int b = bb >> 4, oc = bb & 15;
        bool u8 = mask_mode_u8(pc_mask);
        {
            const float4* p4 = (const float4*)(pts + (b << 10) * 3);
            float4 f0 = p4[3 * t], f1 = p4[3 * t + 1], f2 = p4[3 * t + 2];
            float X[4], Y[4], Z[4];
            UNPACK12(f0, f1, f2, X, Y, Z);
            unsigned m0, m1, m2, m3;
            if (u8) {
                unsigned mw = ((const unsigned*)pc_mask)[(b << 8) + t];
                m0 = mw & 0x000000ffu; m1 = mw & 0x0000ff00u;
                m2 = mw & 0x00ff0000u; m3 = mw & 0xff000000u;
            } else {
                uint4 mi = ((const uint4*)pc_mask)[(b << 8) + t];
                m0 = mi.x; m1 = mi.y; m2 = mi.z; m3 = mi.w;
            }
            unsigned msk[4] = {m0, m1, m2, m3};
#pragma unroll
            for (int u = 0; u < 4; ++u) {
                float ww = fmaf(X[u], X[u], fmaf(Y[u], Y[u], Z[u] * Z[u]));
                lds4[4 * t + u] = msk[u] ? make_float4(X[u], Y[u], Z[u], ww)
                                         : make_float4(0.0f, 0.0f, 0.0f, 3.0e36f);
            }
        }
        int tg = t >> 4, jc = t & 15;
        int j0 = (oc << 6) + (tg << 2);
        float ax[4], ay[4], az[4], pw[4], mm[4];
        load_queries4(recon + ((b << 10) + j0) * 3, ax, ay, az, pw, mm);
        __syncthreads();
        scan4(lds4, jc, ax, ay, az, mm);
#pragma unroll
        for (int u = 0; u < 4; ++u)
            pminS[(tg * 4 + u) * 17 + jc] = pw[u] + mm[u];
        __syncthreads();
        float contrib = 0.0f;
        if (t < 64) {
            float v = INFV;
#pragma unroll
            for (int c = 0; c < 16; ++c) v = fminf(v, pminS[t * 17 + c]);
            contrib = sqrtf(fmaxf(0.0f, v));
        }
        float s = block_sum_t0(contrib, sbuf);
        if (t == 0) ws[W_D2S + bb] = s;

    } else if (blk < 544) {
        // ---- cd: block=(b, half). Stage all 1024 pts; 48 kpts.
        int cc = blk - 512;
        int b = cc >> 1, half = cc & 1;
        {
            const float4* p4 = (const float4*)(pts + (b << 10) * 3);
            float4 f0 = p4[3 * t], f1 = p4[3 * t + 1], f2 = p4[3 * t + 2];
            float X[4], Y[4], Z[4];
            UNPACK12(f0, f1, f2, X, Y, Z);
#pragma unroll
            for (int u = 0; u < 4; ++u)
                lds4[4 * t + u] = make_float4(X[u], Y[u], Z[u],
                    fmaf(X[u], X[u], fmaf(Y[u], Y[u], Z[u] * Z[u])));
        }
        int tg = t >> 4, jc = t & 15;
        float ax[4], ay[4], az[4], pw[4], mm[4];
        bool active = (tg < 12);
        if (active)
            load_queries4(kpt + (b * 96 + half * 48 + (tg << 2)) * 3, ax, ay, az, pw, mm);
        __syncthreads();
        if (active) {
            scan4(lds4, jc, ax, ay, az, mm);
#pragma unroll
            for (int u = 0; u < 4; ++u)
                pminS[(tg * 4 + u) * 17 + jc] = pw[u] + mm[u];
        }
        __syncthreads();
        float contrib = 0.0f;
        if (t < 48) {
            float v = INFV;
#pragma unroll
            for (int c = 0; c < 16; ++c) v = fminf(v, pminS[t * 17 + c]);
            contrib = sqrtf(fmaxf(0.0f, v));
        }
        float s = block_sum_t0(contrib, sbuf);
        if (t == 0) ws[W_CDP + cc] = s;

    } else if (blk < 560) {
        // ---- diversity per batch
        int b = blk - 544;
        const float* K = kpt + b * 288;
        if (t < 96) lds4[t] = make_float4(K[t * 3], K[t * 3 + 1], K[t * 3 + 2], 0.0f);
        __syncthreads();
        float acc = 0.0f;
        for (int r = 0; r < 36; ++r) {
            int p = r * 256 + t;
            int ki = p / 96, kj = p - ki * 96;
            float4 a = lds4[ki], c = lds4[kj];
            float dx = a.x - c.x, dy = a.y - c.y, dz = a.z - c.z;
            float d = sqrtf(dx * dx + dy * dy + dz * dz + 1e-12f);
            if (ki != kj && d < 0.1f) acc += 1.0f - d * 10.0f;
        }
        float s = block_sum_t0(acc, sbuf);
        if (t == 0) ws[W_DIV + b] = s;

    } else if (blk < 576) {
        // ---- recon_delta norms (float4 loads: thread -> 4 points)
        int e = blk - 560;
        const float4* p4 = (const float4*)(recon_delta + e * 1024 * 3);
        float4 f0 = p4[3 * t], f1 = p4[3 * t + 1], f2 = p4[3 * t + 2];
        float X[4], Y[4], Z[4];
        UNPACK12(f0, f1, f2, X, Y, Z);
        float acc = 0.0f;
#pragma unroll
        for (int u = 0; u < 4; ++u)
            acc += sqrtf(fmaf(X[u], X[u], fmaf(Y[u], Y[u], Z[u] * Z[u])));
        float s = block_sum_t0(acc, sbuf);
        if (t == 0) ws[W_DEL + e] = s;

    } else if (blk == 576) {
        // ---- pose (fully normalized)
        float c = 0.0f;
        if (t < 48) {
            int b = t / 3, j = t - b * 3;
            float s = 0.0f;
#pragma unroll
            for (int i2 = 0; i2 < 3; ++i2) {
                float d = pred_r[b * 9 + i2 * 3 + j] - r_label[b * 9 + i2 * 3 + j];
                s += d * d;
            }
            c = sqrtf(s) * (1.0f / 48.0f);
        } else if (t >= 64 && t < 80) {
            int b = t - 64;
            float s = 0.0f;
#pragma unroll
            for (int d2i = 0; d2i < 3; ++d2i) {
                float d = pred_t[b * 3 + d2i] - t_label[b * 3 + d2i];
                s += d * d;
            }
            c = sqrtf(s) * (1.0f / 16.0f);
        } else if (t >= 96 && t < 112) {
            int b = t - 96;
            float s = 0.0f;
#pragma unroll
            for (int d2i = 0; d2i < 3; ++d2i) {
                float d = pred_s[b * 3 + d2i] - s_label[b * 3 + d2i];
                s += d * d;
            }
            c = sqrtf(s) * (1.0f / 16.0f);
        }
        float s = block_sum_t0(c, sbuf);
        if (t == 0) ws[W_POSE] = s;

    } else if (blk == 577) {
        // ---- NOCS smooth-L1
        float acc = 0.0f;
#pragma unroll
        for (int r = 0; r < 6; ++r) {
            int item = r * 256 + t;
            int b = item / 96, k = item - b * 96;
            float sx = s_label[b * 3], sy = s_label[b * 3 + 1], sz = s_label[b * 3 + 2];
            float sn = sqrtf(sx * sx + sy * sy + sz * sz) + 1e-8f;
            float v0 = (kpt[(b * 96 + k) * 3 + 0] - t_label[b * 3 + 0]) / sn;
            float v1 = (kpt[(b * 96 + k) * 3 + 1] - t_label[b * 3 + 1]) / sn;
            float v2 = (kpt[(b * 96 + k) * 3 + 2] - t_label[b * 3 + 2]) / sn;
#pragma unroll
            for (int e = 0; e < 3; ++e) {
                float gt = v0 * r_label[b * 9 + e] + v1 * r_label[b * 9 + 3 + e] +
                           v2 * r_label[b * 9 + 6 + e];
                float diff = fabsf(kpt_nocs[(b * 96 + k) * 3 + e] - gt);
                acc += (diff > 0.1f) ? (diff - 0.05f) : (diff * diff * 5.0f);
            }
        }
        float s = block_sum_t0(acc, sbuf);
        if (t == 0) ws[W_NOCS] = s;

    } else {
        // ---- distillation
        int b = t >> 4, off = t & 15;
        float s = 0.0f;
        for (int c2 = off; c2 < 512; c2 += 16) {
            float d = d_pn[b * 512 + c2] - d_ul[b * 512 + c2];
            s += d * d;
        }
        s += __shfl_xor(s, 1);
        s += __shfl_xor(s, 2);
        s += __shfl_xor(s, 4);
        s += __shfl_xor(s, 8);
        float c = (off == 0) ? sqrtf(s) : 0.0f;
        float sm = block_sum_t0(c, sbuf);
        if (t == 0) ws[W_DIST] = sm;
    }

    // ================= grid-wide barrier, then inline finalize =================
    cg::this_grid().sync();

    if (blk == 0 && t < 64) {
        float vd1 = 0.0f;
        if (t < 16) {
            float s = 0.0f, c = 0.0f;
#pragma unroll
            for (int ic = 0; ic < 16; ++ic) {
                s += ws[W_D1S + t * 16 + ic];
                c += ws[W_D1C + t * 16 + ic];
            }
            vd1 = 0.5f * s / c;
        }
        vd1 = wave_reduce_sum(vd1);

        float vd2 = ws[W_D2S + t] + ws[W_D2S + 64 + t] +
                    ws[W_D2S + 128 + t] + ws[W_D2S + 192 + t];
        vd2 = wave_reduce_sum(vd2);

        float vcd = (t < 32) ? ws[W_CDP + t] : 0.0f;
        vcd = wave_reduce_sum(vcd);

        float vdv = (t < 16) ? ws[W_DIV + t] : 0.0f;
        vdv = wave_reduce_sum(vdv);

        float vdl = (t < 16) ? ws[W_DEL + t] : 0.0f;
        vdl = wave_reduce_sum(vdl);

        if (t == 0) {
            float pose  = ws[W_POSE];
            float nocs  = ws[W_NOCS] * (1.0f / 1536.0f);
            float dist  = ws[W_DIST] * (1.0f / 16.0f);
            float recon = vd1 * (1.0f / 16.0f) + 0.5f * vd2 * (1.0f / 16384.0f);
            float cd    = vcd * (1.0f / 1536.0f);
            float divl  = vdv * (1.0f / (9120.0f * 16.0f));
            float delta = vdl * (1.0f / 16384.0f);
            float all = pose + nocs + cd + divl + recon + delta + dist;
            out[0] = all;  out[1] = pose;  out[2] = nocs;  out[3] = cd;
            out[4] = divl; out[5] = recon; out[6] = delta; out[7] = dist;
        }
    }
}

extern "C" void kernel_launch(void* const* d_in, const int* in_sizes, int n_in,
                              void* d_out, int out_size, void* d_ws, size_t ws_size,
                              hipStream_t stream) {
    const float* pts      = (const float*)d_in[0];
    const float* rdelta   = (const float*)d_in[1];
    const float* kpt      = (const float*)d_in[2];
    const float* recon    = (const float*)d_in[3];
    const float* t_label  = (const float*)d_in[4];
    const float* r_label  = (const float*)d_in[5];
    const float* s_label  = (const float*)d_in[6];
    const float* pred_r   = (const float*)d_in[7];
    const float* pred_t   = (const float*)d_in[8];
    const float* pred_s   = (const float*)d_in[9];
    const float* kptn     = (const float*)d_in[10];
    const void*  pc_mask  = (const void*)d_in[11];
    const float* d_pn     = (const float*)d_in[12];
    const float* d_ul     = (const float*)d_in[13];
    float* ws  = (float*)d_ws;
    float* out = (float*)d_out;

    void* args[] = {
        (void*)&pts, (void*)&rdelta, (void*)&kpt, (void*)&recon,
        (void*)&t_label, (void*)&r_label, (void*)&s_label,
        (void*)&pred_r, (void*)&pred_t, (void*)&pred_s,
        (void*)&kptn, (void*)&pc_mask, (void*)&d_pn, (void*)&d_ul,
        (void*)&ws, (void*)&out
    };
    hipLaunchCooperativeKernel((void*)loss_main, dim3(579), dim3(256),
                               args, 0, stream);
}

// Round 12
// 15.181 us; speedup vs baseline: 5.4804x; 5.4804x over previous
//
#include <hip/hip_runtime.h>

#define INFV 3.0e38f

// ws slot layout (floats) — every slot written unconditionally each call
#define W_D1S 0     // 256: d1 masked sqrt-sum per (b, ic16)
#define W_D1C 256   // 256: mask count per (b, ic16)
#define W_D2S 512   // 256: d2 sqrt-sum per (b, oc16)
#define W_CDP 768   // 32: cd partial per (b, half)
#define W_DIV 800   // 16
#define W_DEL 816   // 16
#define W_POSE 832
#define W_NOCS 833
#define W_DIST 834

__device__ __forceinline__ float wave_reduce_sum(float v) {
#pragma unroll
    for (int m = 1; m < 64; m <<= 1) v += __shfl_xor(v, m);
    return v;
}

// block-wide sum (256 threads)
__device__ __forceinline__ float block_sum_t0(float v, float* sbuf) {
    v = wave_reduce_sum(v);
    int lane = threadIdx.x & 63, wid = threadIdx.x >> 6;
    __syncthreads();
    if (lane == 0) sbuf[wid] = v;
    __syncthreads();
    return sbuf[0] + sbuf[1] + sbuf[2] + sbuf[3];
}

// dual block-wide sum in one barrier round
__device__ __forceinline__ void block_sum2_t0(float v1, float v2, float* sbuf,
                                              float* r1, float* r2) {
    v1 = wave_reduce_sum(v1);
    v2 = wave_reduce_sum(v2);
    int lane = threadIdx.x & 63, wid = threadIdx.x >> 6;
    __syncthreads();
    if (lane == 0) { sbuf[wid] = v1; sbuf[4 + wid] = v2; }
    __syncthreads();
    *r1 = sbuf[0] + sbuf[1] + sbuf[2] + sbuf[3];
    *r2 = sbuf[4] + sbuf[5] + sbuf[6] + sbuf[7];
}

// pc_mask may arrive as u8 (1B) or i32 (4B). Probe bytes at 4i+1 (wave-wide).
__device__ __forceinline__ bool mask_mode_u8(const void* mp) {
    const unsigned char* p = (const unsigned char*)mp;
    unsigned char v = p[(threadIdx.x & 63) * 4 + 1];
    return __ballot(v != 0) != 0ull;
}
__device__ __forceinline__ bool mask_at(const void* mp, int idx, bool u8) {
    if (u8) return ((const unsigned char*)mp)[idx] != 0;
    return ((const int*)mp)[idx] != 0;
}

// unpack 3 float4 (12 floats) into 4 xyz points
#define UNPACK12(f0, f1, f2, X, Y, Z) { \
    X[0]=f0.x; Y[0]=f0.y; Z[0]=f0.z; \
    X[1]=f0.w; Y[1]=f1.x; Z[1]=f1.y; \
    X[2]=f1.z; Y[2]=f1.w; Z[2]=f2.x; \
    X[3]=f2.y; Y[3]=f2.z; Z[3]=f2.w; }

// 4-query scan over this thread's j-class (64 staged points, stride 16)
__device__ __forceinline__ void scan4(const float4* lds4, int jc,
                                      const float* ax, const float* ay,
                                      const float* az, float* mm) {
    for (int r = 0; r < 64; r += 4) {
        float4 q0 = lds4[((r + 0) << 4) + jc];
        float4 q1 = lds4[((r + 1) << 4) + jc];
        float4 q2 = lds4[((r + 2) << 4) + jc];
        float4 q3 = lds4[((r + 3) << 4) + jc];
#pragma unroll
        for (int u = 0; u < 4; ++u)
            mm[u] = fminf(mm[u], fmaf(ax[u], q0.x, fmaf(ay[u], q0.y, fmaf(az[u], q0.z, q0.w))));
#pragma unroll
        for (int u = 0; u < 4; ++u)
            mm[u] = fminf(mm[u], fmaf(ax[u], q1.x, fmaf(ay[u], q1.y, fmaf(az[u], q1.z, q1.w))));
#pragma unroll
        for (int u = 0; u < 4; ++u)
            mm[u] = fminf(mm[u], fmaf(ax[u], q2.x, fmaf(ay[u], q2.y, fmaf(az[u], q2.z, q2.w))));
#pragma unroll
        for (int u = 0; u < 4; ++u)
            mm[u] = fminf(mm[u], fmaf(ax[u], q3.x, fmaf(ay[u], q3.y, fmaf(az[u], q3.z, q3.w))));
    }
}

// load 4 consecutive points as 3 float4, derive scan coefficients
__device__ __forceinline__ void load_queries4(const float* base,
                                              float* ax, float* ay, float* az,
                                              float* pw, float* mm) {
    const float4* q4 = (const float4*)base;
    float4 g0 = q4[0], g1 = q4[1], g2 = q4[2];
    float X[4], Y[4], Z[4];
    UNPACK12(g0, g1, g2, X, Y, Z);
#pragma unroll
    for (int u = 0; u < 4; ++u) {
        ax[u] = -2.0f * X[u]; ay[u] = -2.0f * Y[u]; az[u] = -2.0f * Z[u];
        pw[u] = fmaf(X[u], X[u], fmaf(Y[u], Y[u], Z[u] * Z[u]));
        mm[u] = INFV;
    }
}

// Role order chosen for CU packing: blocks dispatch ~round-robin over 256 CUs.
//  [0..31]   cd (heavy)
//  [32..47]  diversity
//  [48..63]  recon_delta
//  [64]      pose   [65] nocs   [66] dist
//  [67..322] d1 (heavy)
//  [323..578] d2 (heavy)
// => every CU hosts at most 2 heavy blocks (+ maybe 1 tiny), no 3-heavy CU.
__global__ __launch_bounds__(256) void loss_main(
    const float* __restrict__ pts,          // (16,1024,3)
    const float* __restrict__ recon_delta,  // (16,1024,3)
    const float* __restrict__ kpt,          // (16,96,3)
    const float* __restrict__ recon,        // (16,1024,3)
    const float* __restrict__ t_label,      // (16,3)
    const float* __restrict__ r_label,      // (16,3,3)
    const float* __restrict__ s_label,      // (16,3)
    const float* __restrict__ pred_r,       // (16,3,3)
    const float* __restrict__ pred_t,       // (16,3)
    const float* __restrict__ pred_s,       // (16,3)
    const float* __restrict__ kpt_nocs,     // (16,96,3)
    const void*  __restrict__ pc_mask,      // (16,1024) bool
    const float* __restrict__ d_pn,         // (16,512)
    const float* __restrict__ d_ul,         // (16,512)
    float* __restrict__ ws)
{
    __shared__ float4 lds4[1024];
    __shared__ float pminS[1088];   // 64 rows x stride 17 (pad -> conflict-free)
    __shared__ float sbuf[8];
    const int t = threadIdx.x;
    const int blk = blockIdx.x;

    if (blk < 32) {
        // ---- cd: block=(b, half). Stage all 1024 pts; 48 kpts.
        int b = blk >> 1, half = blk & 1;
        {
            const float4* p4 = (const float4*)(pts + (b << 10) * 3);
            float4 f0 = p4[3 * t], f1 = p4[3 * t + 1], f2 = p4[3 * t + 2];
            float X[4], Y[4], Z[4];
            UNPACK12(f0, f1, f2, X, Y, Z);
#pragma unroll
            for (int u = 0; u < 4; ++u)
                lds4[4 * t + u] = make_float4(X[u], Y[u], Z[u],
                    fmaf(X[u], X[u], fmaf(Y[u], Y[u], Z[u] * Z[u])));
        }
        int tg = t >> 4, jc = t & 15;
        float ax[4], ay[4], az[4], pw[4], mm[4];
        bool active = (tg < 12);
        if (active)
            load_queries4(kpt + (b * 96 + half * 48 + (tg << 2)) * 3, ax, ay, az, pw, mm);
        __syncthreads();
        if (active) {
            scan4(lds4, jc, ax, ay, az, mm);
#pragma unroll
            for (int u = 0; u < 4; ++u)
                pminS[(tg * 4 + u) * 17 + jc] = pw[u] + mm[u];
        }
        __syncthreads();
        float contrib = 0.0f;
        if (t < 48) {
            float v = INFV;
#pragma unroll
            for (int c = 0; c < 16; ++c) v = fminf(v, pminS[t * 17 + c]);
            contrib = sqrtf(fmaxf(0.0f, v));
        }
        float s = block_sum_t0(contrib, sbuf);
        if (t == 0) ws[W_CDP + blk] = s;

    } else if (blk < 48) {
        // ---- diversity per batch
        int b = blk - 32;
        const float* K = kpt + b * 288;
        if (t < 96) lds4[t] = make_float4(K[t * 3], K[t * 3 + 1], K[t * 3 + 2], 0.0f);
        __syncthreads();
        float acc = 0.0f;
        for (int r = 0; r < 36; ++r) {
            int p = r * 256 + t;
            int ki = p / 96, kj = p - ki * 96;
            float4 a = lds4[ki], c = lds4[kj];
            float dx = a.x - c.x, dy = a.y - c.y, dz = a.z - c.z;
            float d = sqrtf(dx * dx + dy * dy + dz * dz + 1e-12f);
            if (ki != kj && d < 0.1f) acc += 1.0f - d * 10.0f;
        }
        float s = block_sum_t0(acc, sbuf);
        if (t == 0) ws[W_DIV + b] = s;

    } else if (blk < 64) {
        // ---- recon_delta norms (float4 loads: thread -> 4 points)
        int e = blk - 48;
        const float4* p4 = (const float4*)(recon_delta + e * 1024 * 3);
        float4 f0 = p4[3 * t], f1 = p4[3 * t + 1], f2 = p4[3 * t + 2];
        float X[4], Y[4], Z[4];
        UNPACK12(f0, f1, f2, X, Y, Z);
        float acc = 0.0f;
#pragma unroll
        for (int u = 0; u < 4; ++u)
            acc += sqrtf(fmaf(X[u], X[u], fmaf(Y[u], Y[u], Z[u] * Z[u])));
        float s = block_sum_t0(acc, sbuf);
        if (t == 0) ws[W_DEL + e] = s;

    } else if (blk == 64) {
        // ---- pose (fully normalized)
        float c = 0.0f;
        if (t < 48) {
            int b = t / 3, j = t - b * 3;
            float s = 0.0f;
#pragma unroll
            for (int i2 = 0; i2 < 3; ++i2) {
                float d = pred_r[b * 9 + i2 * 3 + j] - r_label[b * 9 + i2 * 3 + j];
                s += d * d;
            }
            c = sqrtf(s) * (1.0f / 48.0f);
        } else if (t >= 64 && t < 80) {
            int b = t - 64;
            float s = 0.0f;
#pragma unroll
            for (int d2i = 0; d2i < 3; ++d2i) {
                float d = pred_t[b * 3 + d2i] - t_label[b * 3 + d2i];
                s += d * d;
            }
            c = sqrtf(s) * (1.0f / 16.0f);
        } else if (t >= 96 && t < 112) {
            int b = t - 96;
            float s = 0.0f;
#pragma unroll
            for (int d2i = 0; d2i < 3; ++d2i) {
                float d = pred_s[b * 3 + d2i] - s_label[b * 3 + d2i];
                s += d * d;
            }
            c = sqrtf(s) * (1.0f / 16.0f);
        }
        float s = block_sum_t0(c, sbuf);
        if (t == 0) ws[W_POSE] = s;

    } else if (blk == 65) {
        // ---- NOCS smooth-L1
        float acc = 0.0f;
#pragma unroll
        for (int r = 0; r < 6; ++r) {
            int item = r * 256 + t;
            int b = item / 96, k = item - b * 96;
            float sx = s_label[b * 3], sy = s_label[b * 3 + 1], sz = s_label[b * 3 + 2];
            float sn = sqrtf(sx * sx + sy * sy + sz * sz) + 1e-8f;
            float v0 = (kpt[(b * 96 + k) * 3 + 0] - t_label[b * 3 + 0]) / sn;
            float v1 = (kpt[(b * 96 + k) * 3 + 1] - t_label[b * 3 + 1]) / sn;
            float v2 = (kpt[(b * 96 + k) * 3 + 2] - t_label[b * 3 + 2]) / sn;
#pragma unroll
            for (int e = 0; e < 3; ++e) {
                float gt = v0 * r_label[b * 9 + e] + v1 * r_label[b * 9 + 3 + e] +
                           v2 * r_label[b * 9 + 6 + e];
                float diff = fabsf(kpt_nocs[(b * 96 + k) * 3 + e] - gt);
                acc += (diff > 0.1f) ? (diff - 0.05f) : (diff * diff * 5.0f);
            }
        }
        float s = block_sum_t0(acc, sbuf);
        if (t == 0) ws[W_NOCS] = s;

    } else if (blk == 66) {
        // ---- distillation
        int b = t >> 4, off = t & 15;
        float s = 0.0f;
        for (int c2 = off; c2 < 512; c2 += 16) {
            float d = d_pn[b * 512 + c2] - d_ul[b * 512 + c2];
            s += d * d;
        }
        s += __shfl_xor(s, 1);
        s += __shfl_xor(s, 2);
        s += __shfl_xor(s, 4);
        s += __shfl_xor(s, 8);
        float c = (off == 0) ? sqrtf(s) : 0.0f;
        float sm = block_sum_t0(c, sbuf);
        if (t == 0) ws[W_DIST] = sm;

    } else if (blk < 323) {
        // ---- d1: block=(b, ic of 16). Stage ALL 1024 recon pts of b.
        int bb = blk - 67;
        int b = bb >> 4, ic = bb & 15;
        bool u8 = mask_mode_u8(pc_mask);
        {
            const float4* p4 = (const float4*)(recon + (b << 10) * 3);
            float4 f0 = p4[3 * t], f1 = p4[3 * t + 1], f2 = p4[3 * t + 2];
            float X[4], Y[4], Z[4];
            UNPACK12(f0, f1, f2, X, Y, Z);
#pragma unroll
            for (int u = 0; u < 4; ++u)
                lds4[4 * t + u] = make_float4(X[u], Y[u], Z[u],
                    fmaf(X[u], X[u], fmaf(Y[u], Y[u], Z[u] * Z[u])));
        }
        int tg = t >> 4, jc = t & 15;
        int i0 = (ic << 6) + (tg << 2);       // 4 queries per thread
        float ax[4], ay[4], az[4], pw[4], mm[4];
        load_queries4(pts + ((b << 10) + i0) * 3, ax, ay, az, pw, mm);
        __syncthreads();
        scan4(lds4, jc, ax, ay, az, mm);
#pragma unroll
        for (int u = 0; u < 4; ++u)
            pminS[(tg * 4 + u) * 17 + jc] = pw[u] + mm[u];
        __syncthreads();
        float contrib_s = 0.0f, contrib_c = 0.0f;
        if (t < 64) {
            float v = INFV;
#pragma unroll
            for (int c = 0; c < 16; ++c) v = fminf(v, pminS[t * 17 + c]);
            float d = sqrtf(fmaxf(0.0f, v));
            float mv = mask_at(pc_mask, (b << 10) + (ic << 6) + t, u8) ? 1.0f : 0.0f;
            contrib_s = d * mv;
            contrib_c = mv;
        }
        float s, c;
        block_sum2_t0(contrib_s, contrib_c, sbuf, &s, &c);
        if (t == 0) { ws[W_D1S + bb] = s; ws[W_D1C + bb] = c; }

    } else {
        // ---- d2: block=(b, oc of 16). Stage ALL 1024 pts masked->(0,0,0,3e36).
        int bb = blk - 323;
        int b = bb >> 4, oc = bb & 15;
        bool u8 = mask_mode_u8(pc_mask);
        {
            const float4* p4 = (const float4*)(pts + (b << 10) * 3);
            float4 f0 = p4[3 * t], f1 = p4[3 * t + 1], f2 = p4[3 * t + 2];
            float X[4], Y[4], Z[4];
            UNPACK12(f0, f1, f2, X, Y, Z);
            unsigned m0, m1, m2, m3;
            if (u8) {
                unsigned mw = ((const unsigned*)pc_mask)[(b << 8) + t];
                m0 = mw & 0x000000ffu; m1 = mw & 0x0000ff00u;
                m2 = mw & 0x00ff0000u; m3 = mw & 0xff000000u;
            } else {
                uint4 mi = ((const uint4*)pc_mask)[(b << 8) + t];
                m0 = mi.x; m1 = mi.y; m2 = mi.z; m3 = mi.w;
            }
            unsigned msk[4] = {m0, m1, m2, m3};
#pragma unroll
            for (int u = 0; u < 4; ++u) {
                float ww = fmaf(X[u], X[u], fmaf(Y[u], Y[u], Z[u] * Z[u]));
                lds4[4 * t + u] = msk[u] ? make_float4(X[u], Y[u], Z[u], ww)
                                         : make_float4(0.0f, 0.0f, 0.0f, 3.0e36f);
            }
        }
        int tg = t >> 4, jc = t & 15;
        int j0 = (oc << 6) + (tg << 2);
        float ax[4], ay[4], az[4], pw[4], mm[4];
        load_queries4(recon + ((b << 10) + j0) * 3, ax, ay, az, pw, mm);
        __syncthreads();
        scan4(lds4, jc, ax, ay, az, mm);
#pragma unroll
        for (int u = 0; u < 4; ++u)
            pminS[(tg * 4 + u) * 17 + jc] = pw[u] + mm[u];
        __syncthreads();
        float contrib = 0.0f;
        if (t < 64) {
            float v = INFV;
#pragma unroll
            for (int c = 0; c < 16; ++c) v = fminf(v, pminS[t * 17 + c]);
            contrib = sqrtf(fmaxf(0.0f, v));
        }
        float s = block_sum_t0(contrib, sbuf);
        if (t == 0) ws[W_D2S + bb] = s;
    }
}

__global__ __launch_bounds__(64) void loss_finalize(const float* __restrict__ ws,
                                                    float* __restrict__ out) {
    int t = threadIdx.x;

    float vd1 = 0.0f;
    if (t < 16) {
        float s = 0.0f, c = 0.0f;
#pragma unroll
        for (int ic = 0; ic < 16; ++ic) {
            s += ws[W_D1S + t * 16 + ic];
            c += ws[W_D1C + t * 16 + ic];
        }
        vd1 = 0.5f * s / c;
    }
    vd1 = wave_reduce_sum(vd1);

    float vd2 = ws[W_D2S + t] + ws[W_D2S + 64 + t] +
                ws[W_D2S + 128 + t] + ws[W_D2S + 192 + t];
    vd2 = wave_reduce_sum(vd2);

    float vcd = (t < 32) ? ws[W_CDP + t] : 0.0f;
    vcd = wave_reduce_sum(vcd);

    float vdv = (t < 16) ? ws[W_DIV + t] : 0.0f;
    vdv = wave_reduce_sum(vdv);

    float vdl = (t < 16) ? ws[W_DEL + t] : 0.0f;
    vdl = wave_reduce_sum(vdl);

    if (t == 0) {
        float pose  = ws[W_POSE];
        float nocs  = ws[W_NOCS] * (1.0f / 1536.0f);
        float dist  = ws[W_DIST] * (1.0f / 16.0f);
        float recon = vd1 * (1.0f / 16.0f) + 0.5f * vd2 * (1.0f / 16384.0f);
        float cd    = vcd * (1.0f / 1536.0f);
        float divl  = vdv * (1.0f / (9120.0f * 16.0f));
        float delta = vdl * (1.0f / 16384.0f);
        float all = pose + nocs + cd + divl + recon + delta + dist;
        out[0] = all;  out[1] = pose;  out[2] = nocs;  out[3] = cd;
        out[4] = divl; out[5] = recon; out[6] = delta; out[7] = dist;
    }
}

extern "C" void kernel_launch(void* const* d_in, const int* in_sizes, int n_in,
                              void* d_out, int out_size, void* d_ws, size_t ws_size,
                              hipStream_t stream) {
    float* ws = (float*)d_ws;
    loss_main<<<579, 256, 0, stream>>>(
        (const float*)d_in[0],  (const float*)d_in[1],  (const float*)d_in[2],
        (const float*)d_in[3],  (const float*)d_in[4],  (const float*)d_in[5],
        (const float*)d_in[6],  (const float*)d_in[7],  (const float*)d_in[8],
        (const float*)d_in[9],  (const float*)d_in[10], (const void*)d_in[11],
        (const float*)d_in[12], (const float*)d_in[13], ws);
    loss_finalize<<<1, 64, 0, stream>>>(ws, (float*)d_out);
}